// Round 2
// baseline (59.033 us; speedup 1.0000x reference)
//
#include <hip/hip_runtime.h>
#include <hip/hip_bf16.h>
#include <climits>

// Problem constants: B=8, C=8, H=512, W=512
#define HWSZ 262144      // H*W
#define CHWSZ 2097152    // C*H*W

typedef short short8 __attribute__((ext_vector_type(8)));   // 8 bf16 (4 VGPRs)
typedef float f32x4 __attribute__((ext_vector_type(4)));    // MFMA accumulator
typedef float f4 __attribute__((ext_vector_type(4)));       // component-indexable float4
typedef unsigned short u16x8 __attribute__((ext_vector_type(8)));  // 16B label store

// ---------------- init: INT_MAX mins (x2/y2 written directly by hd_norms) ----------------
__global__ __launch_bounds__(256) void hd_init(int* rowmin, int* colmin) {
    int i = blockIdx.x * 256 + threadIdx.x;   // grid 16*256 = 4096 exactly
    rowmin[i] = INT_MAX;
    colmin[i] = INT_MAX;
}

// ---------------- argmax + bf16 label write ----------------
// 8 px/thread. All 16 float4 loads of a phase are issued before any compare so
// they stay in flight together (VGPR-heavy on purpose — R1 showed VGPR=24 meant
// the compiler serialized load->wait->compare, leaving every pipe idle).
__global__ __launch_bounds__(256) void hd_argmax(const float* __restrict__ logits,
                                                 const float* __restrict__ target,
                                                 ushort* __restrict__ lxb,
                                                 ushort* __restrict__ tyb) {
    int t = blockIdx.x * 256 + threadIdx.x;   // 0 .. 256K-1
    int p = t << 3;                           // pixel index (8 px per thread)
    int b = p >> 18;                          // / (H*W)
    int off = p & (HWSZ - 1);

    const f4* L = (const f4*)(logits + (size_t)b * CHWSZ + off);
    const f4* T = (const f4*)(target + (size_t)b * CHWSZ + off);

    // ---- logits: issue all 16 loads, then compare ----
    f4 v[16];
#pragma unroll
    for (int c = 0; c < 8; ++c) {
        v[2 * c]     = L[c * (HWSZ / 4)];
        v[2 * c + 1] = L[c * (HWSZ / 4) + 1];
    }
    u16x8 ub;
#pragma unroll
    for (int half = 0; half < 2; ++half) {
#pragma unroll
        for (int j = 0; j < 4; ++j) {
            float bv = v[half][j];
            int bi = 0;
#pragma unroll
            for (int c = 1; c < 8; ++c) {
                float x = v[2 * c + half][j];
                bool g = x > bv;            // strict > keeps first max (jnp.argmax)
                bv = g ? x : bv;
                bi = g ? c : bi;
            }
            ub[half * 4 + j] = (ushort)(__float_as_uint((float)bi) >> 16);  // exact bf16 0..7
        }
    }
    *(u16x8*)(lxb + p) = ub;

    // ---- target: same ----
    f4 w[16];
#pragma unroll
    for (int c = 0; c < 8; ++c) {
        w[2 * c]     = T[c * (HWSZ / 4)];
        w[2 * c + 1] = T[c * (HWSZ / 4) + 1];
    }
    u16x8 wb;
#pragma unroll
    for (int half = 0; half < 2; ++half) {
#pragma unroll
        for (int j = 0; j < 4; ++j) {
            float bv = w[half][j];
            int bi = 0;
#pragma unroll
            for (int c = 1; c < 8; ++c) {
                float x = w[2 * c + half][j];
                bool g = x > bv;
                bv = g ? x : bv;
                bi = g ? c : bi;
            }
            wb[half * 4 + j] = (ushort)(__float_as_uint((float)bi) >> 16);
        }
    }
    *(u16x8*)(tyb + p) = wb;
}

// ---------------- row norms from bf16 labels: one wave per row, no atomics ----------------
__global__ __launch_bounds__(256) void hd_norms(const ushort* __restrict__ lxb,
                                                const ushort* __restrict__ tyb,
                                                float* __restrict__ x2,
                                                float* __restrict__ y2) {
    int wid = blockIdx.x * 4 + (threadIdx.x >> 6);   // 0..8191
    int l = threadIdx.x & 63;
    const ushort* src = (wid < 4096) ? (lxb + wid * 512) : (tyb + (wid - 4096) * 512);
    u16x8 u = *(const u16x8*)(src + l * 8);
    float s = 0.0f;
#pragma unroll
    for (int j = 0; j < 8; ++j) {
        float f = __uint_as_float((unsigned)u[j] << 16);
        s += f * f;
    }
#pragma unroll
    for (int o = 32; o > 0; o >>= 1) s += __shfl_xor(s, o, 64);
    if (l == 0) {
        if (wid < 4096) x2[wid] = s; else y2[wid - 4096] = s;
    }
}

// ---------------- 64x64-tile MFMA distance kernel ----------------
// Grid (64, 8): blockIdx.x = ti*8+tj tile of the 512x512 distance matrix, blockIdx.y = batch.
// 4 waves per block, wave (wr,wc) owns a 32x32 quadrant as 2x2 MFMA 16x16x32 frags.
// Fragments load straight from global (label maps are 512KB/batch -> L2-hot).
// d2 = x2[i] + y2[j] - 2*<x_i,y_j>  (exact integer), reduced via shfl + atomicMin.
__global__ __launch_bounds__(256) void hd_dist(const ushort* __restrict__ lxb,
                                               const ushort* __restrict__ tyb,
                                               const float* __restrict__ x2,
                                               const float* __restrict__ y2,
                                               int* __restrict__ rowmin,
                                               int* __restrict__ colmin) {
    int b = blockIdx.y;
    int ti = blockIdx.x >> 3, tj = blockIdx.x & 7;
    int tid = threadIdx.x;
    int l = tid & 63;
    int wv = tid >> 6;
    int wr = wv >> 1, wc = wv & 1;
    int lr = l & 15, lg = l >> 4;

    const ushort* X = lxb + b * HWSZ + (ti * 64 + wr * 32 + lr) * 512 + lg * 8;
    const ushort* Y = tyb + b * HWSZ + (tj * 64 + wc * 32 + lr) * 512 + lg * 8;

    f32x4 acc00 = {0.f, 0.f, 0.f, 0.f};
    f32x4 acc01 = {0.f, 0.f, 0.f, 0.f};
    f32x4 acc10 = {0.f, 0.f, 0.f, 0.f};
    f32x4 acc11 = {0.f, 0.f, 0.f, 0.f};

#pragma unroll 4
    for (int kk = 0; kk < 512; kk += 32) {
        short8 a0 = *(const short8*)(X + kk);
        short8 a1 = *(const short8*)(X + 8192 + kk);   // +16 rows
        short8 b0 = *(const short8*)(Y + kk);
        short8 b1 = *(const short8*)(Y + 8192 + kk);
        acc00 = __builtin_amdgcn_mfma_f32_16x16x32_bf16(a0, b0, acc00, 0, 0, 0);
        acc01 = __builtin_amdgcn_mfma_f32_16x16x32_bf16(a0, b1, acc01, 0, 0, 0);
        acc10 = __builtin_amdgcn_mfma_f32_16x16x32_bf16(a1, b0, acc10, 0, 0, 0);
        acc11 = __builtin_amdgcn_mfma_f32_16x16x32_bf16(a1, b1, acc11, 0, 0, 0);
    }

    // epilogue: norms + exact integer d2
    int rb = (b << 9) + ti * 64 + wr * 32;   // global row base (into per-batch 512)
    int cb = (b << 9) + tj * 64 + wc * 32;   // global col base
    float x2v0[4], x2v1[4];
#pragma unroll
    for (int r = 0; r < 4; ++r) {
        x2v0[r] = x2[rb + lg * 4 + r];
        x2v1[r] = x2[rb + 16 + lg * 4 + r];
    }
    float y2v0 = y2[cb + lr];
    float y2v1 = y2[cb + 16 + lr];

    int d2[2][2][4];
#pragma unroll
    for (int r = 0; r < 4; ++r) {
        d2[0][0][r] = (int)(fmaxf(fmaf(-2.0f, acc00[r], x2v0[r] + y2v0), 0.0f) + 0.5f);
        d2[0][1][r] = (int)(fmaxf(fmaf(-2.0f, acc01[r], x2v0[r] + y2v1), 0.0f) + 0.5f);
        d2[1][0][r] = (int)(fmaxf(fmaf(-2.0f, acc10[r], x2v1[r] + y2v0), 0.0f) + 0.5f);
        d2[1][1][r] = (int)(fmaxf(fmaf(-2.0f, acc11[r], x2v1[r] + y2v1), 0.0f) + 0.5f);
    }

    // row mins: row r is held by the 16 lanes sharing lg, one col each (C layout: col=l&15)
#pragma unroll
    for (int fi = 0; fi < 2; ++fi) {
#pragma unroll
        for (int r = 0; r < 4; ++r) {
            int m = min(d2[fi][0][r], d2[fi][1][r]);
            m = min(m, __shfl_xor(m, 1, 64));
            m = min(m, __shfl_xor(m, 2, 64));
            m = min(m, __shfl_xor(m, 4, 64));
            m = min(m, __shfl_xor(m, 8, 64));
            if (lr == 0) atomicMin(&rowmin[rb + fi * 16 + lg * 4 + r], m);
        }
    }
    // col mins: col is fixed per lane within a frag; reduce across the 4 lane-groups
#pragma unroll
    for (int fj = 0; fj < 2; ++fj) {
        int m;
        if (fj == 0) {
            m = min(min(min(d2[0][0][0], d2[0][0][1]), min(d2[0][0][2], d2[0][0][3])),
                    min(min(d2[1][0][0], d2[1][0][1]), min(d2[1][0][2], d2[1][0][3])));
        } else {
            m = min(min(min(d2[0][1][0], d2[0][1][1]), min(d2[0][1][2], d2[0][1][3])),
                    min(min(d2[1][1][0], d2[1][1][1]), min(d2[1][1][2], d2[1][1][3])));
        }
        m = min(m, __shfl_xor(m, 16, 64));
        m = min(m, __shfl_xor(m, 32, 64));
        if (lg == 0) atomicMin(&colmin[cb + fj * 16 + lr], m);
    }
}

// ---------------- final: per-batch max over (rowmin ∪ colmin), sqrt, mean ----------------
__global__ __launch_bounds__(512) void hd_final(const int* __restrict__ rowmin,
                                                const int* __restrict__ colmin,
                                                float* __restrict__ out) {
    int w = threadIdx.x >> 6, l = threadIdx.x & 63;   // wave w = batch w
    int m = 0;
#pragma unroll
    for (int j = 0; j < 512; j += 64) {
        m = max(m, rowmin[(w << 9) + j + l]);
        m = max(m, colmin[(w << 9) + j + l]);
    }
#pragma unroll
    for (int s = 32; s > 0; s >>= 1) m = max(m, __shfl_xor(m, s, 64));
    __shared__ float hd[8];
    if (l == 0) hd[w] = sqrtf((float)m);
    __syncthreads();
    if (threadIdx.x == 0) {
        float s = 0.0f;
#pragma unroll
        for (int i = 0; i < 8; ++i) s += hd[i];
        out[0] = s * 0.125f;
    }
}

extern "C" void kernel_launch(void* const* d_in, const int* in_sizes, int n_in,
                              void* d_out, int out_size, void* d_ws, size_t ws_size,
                              hipStream_t stream) {
    (void)in_sizes; (void)n_in; (void)out_size; (void)ws_size;
    const float* logits = (const float*)d_in[0];
    const float* target = (const float*)d_in[1];

    char* ws = (char*)d_ws;
    ushort* lxb = (ushort*)ws;                          // 2M bf16 = 4 MB
    ushort* tyb = (ushort*)(ws + (4u << 20));           // 4 MB
    float* x2   = (float*)(ws + (8u << 20));            // 4096 f32
    float* y2   = x2 + 4096;                            // 4096 f32
    int* rowmin = (int*)(y2 + 4096);                    // 4096 i32
    int* colmin = rowmin + 4096;                        // 4096 i32
    float* out  = (float*)d_out;

    hipLaunchKernelGGL(hd_init,   dim3(16),    dim3(256), 0, stream, rowmin, colmin);
    hipLaunchKernelGGL(hd_argmax, dim3(1024),  dim3(256), 0, stream, logits, target, lxb, tyb);
    hipLaunchKernelGGL(hd_norms,  dim3(2048),  dim3(256), 0, stream, lxb, tyb, x2, y2);
    hipLaunchKernelGGL(hd_dist,   dim3(64, 8), dim3(256), 0, stream, lxb, tyb, x2, y2, rowmin, colmin);
    hipLaunchKernelGGL(hd_final,  dim3(1),     dim3(512), 0, stream, rowmin, colmin, out);
}

// Round 3
// 54.642 us; speedup vs baseline: 1.0804x; 1.0804x over previous
//
#include <hip/hip_runtime.h>
#include <hip/hip_bf16.h>
#include <climits>

// Problem constants: B=8, C=8, H=512, W=512
#define HWSZ 262144      // H*W
#define CHWSZ 2097152    // C*H*W

typedef short short8 __attribute__((ext_vector_type(8)));   // 8 bf16 (4 VGPRs)
typedef float f32x4 __attribute__((ext_vector_type(4)));    // MFMA accumulator
typedef unsigned short u16x8 __attribute__((ext_vector_type(8)));  // 16B label chunk

#define GLOAD_LDS16(gp, lp)                                                        \
    __builtin_amdgcn_global_load_lds(                                              \
        (const __attribute__((address_space(1))) unsigned int*)(gp),               \
        (__attribute__((address_space(3))) unsigned int*)(lp), 16, 0, 0)

// ---------------- init: INT_MAX mins ----------------
__global__ __launch_bounds__(256) void hd_init(int* rowmin, int* colmin) {
    int i = blockIdx.x * 256 + threadIdx.x;   // grid 16*256 = 4096 exactly
    rowmin[i] = INT_MAX;
    colmin[i] = INT_MAX;
}

// ---------------- argmax via global_load_lds staging ----------------
// Block = 256 threads = 4 waves, covers 512 contiguous pixels (never crosses a batch:
// 512 | HWSZ). Stage: 32 fire-and-forget DMA loads (8 per wave, 1 KB each) fill
// lds[2][8][512] (32 KB). The DMA queue guarantees all 32 are in flight together —
// R1/R2 showed the compiler serializes register loads to ~1 in flight (45 us at 5%
// VALUBusy even with L3-resident data). Then barrier, 8-way argmax from LDS, ushort2
// label stores.
__global__ __launch_bounds__(256) void hd_argmax(const float* __restrict__ logits,
                                                 const float* __restrict__ target,
                                                 ushort* __restrict__ lxb,
                                                 ushort* __restrict__ tyb) {
    __shared__ float lds[2][8][512];   // 32 KB
    int t = threadIdx.x;
    int l = t & 63, w = t >> 6;
    int blockpx = blockIdx.x * 512;
    int b = blockpx >> 18;
    int off = blockpx & (HWSZ - 1);
    const float* base0 = logits + (size_t)b * CHWSZ + off;
    const float* base1 = target + (size_t)b * CHWSZ + off;

#pragma unroll
    for (int i = 0; i < 8; ++i) {
        int idx = w * 8 + i;                 // 0..31, wave-uniform
        int in = idx >> 4;                   // 0: logits, 1: target
        int ch = (idx >> 1) & 7;
        int hf = idx & 1;                    // half of the 512-px stripe
        const float* gp = (in ? base1 : base0) + ch * HWSZ + hf * 256 + l * 4;  // per-lane 16B
        GLOAD_LDS16(gp, &lds[in][ch][hf * 256]);                                // wave-uniform dest
    }
    __syncthreads();   // compiler emits s_waitcnt vmcnt(0) before the barrier

    // thread t owns pixels blockpx + 2t, 2t+1
#pragma unroll
    for (int in = 0; in < 2; ++in) {
        float2 v0 = *(const float2*)&lds[in][0][t * 2];
        float bx = v0.x, by = v0.y;
        int ix = 0, iy = 0;
#pragma unroll
        for (int c = 1; c < 8; ++c) {
            float2 v = *(const float2*)&lds[in][c][t * 2];
            if (v.x > bx) { bx = v.x; ix = c; }   // strict >: first-max, matches jnp.argmax
            if (v.y > by) { by = v.y; iy = c; }
        }
        ushort2 u;
        u.x = (ushort)(__float_as_uint((float)ix) >> 16);   // exact bf16 for 0..7
        u.y = (ushort)(__float_as_uint((float)iy) >> 16);
        ushort* dst = (in ? tyb : lxb) + blockpx + t * 2;
        *(ushort2*)dst = u;
    }
}

// ---------------- row norms from bf16 labels: one wave per row, no atomics ----------------
__global__ __launch_bounds__(256) void hd_norms(const ushort* __restrict__ lxb,
                                                const ushort* __restrict__ tyb,
                                                float* __restrict__ x2,
                                                float* __restrict__ y2) {
    int wid = blockIdx.x * 4 + (threadIdx.x >> 6);   // 0..8191
    int l = threadIdx.x & 63;
    const ushort* src = (wid < 4096) ? (lxb + wid * 512) : (tyb + (wid - 4096) * 512);
    u16x8 u = *(const u16x8*)(src + l * 8);
    float s = 0.0f;
#pragma unroll
    for (int j = 0; j < 8; ++j) {
        float f = __uint_as_float((unsigned)u[j] << 16);
        s += f * f;
    }
#pragma unroll
    for (int o = 32; o > 0; o >>= 1) s += __shfl_xor(s, o, 64);
    if (l == 0) {
        if (wid < 4096) x2[wid] = s; else y2[wid - 4096] = s;
    }
}

// ---------------- 64x64-tile MFMA distance kernel ----------------
// Grid (64, 8). 4 waves/block, wave (wr,wc) owns a 32x32 quadrant as 2x2 16x16x32 frags.
// Fragments load straight from global (label maps are 512KB/batch -> L2-hot).
// d2 = x2[i] + y2[j] - 2*<x_i,y_j> (exact integer), reduced via shfl + atomicMin.
__global__ __launch_bounds__(256) void hd_dist(const ushort* __restrict__ lxb,
                                               const ushort* __restrict__ tyb,
                                               const float* __restrict__ x2,
                                               const float* __restrict__ y2,
                                               int* __restrict__ rowmin,
                                               int* __restrict__ colmin) {
    int b = blockIdx.y;
    int ti = blockIdx.x >> 3, tj = blockIdx.x & 7;
    int tid = threadIdx.x;
    int l = tid & 63;
    int wv = tid >> 6;
    int wr = wv >> 1, wc = wv & 1;
    int lr = l & 15, lg = l >> 4;

    const ushort* X = lxb + b * HWSZ + (ti * 64 + wr * 32 + lr) * 512 + lg * 8;
    const ushort* Y = tyb + b * HWSZ + (tj * 64 + wc * 32 + lr) * 512 + lg * 8;

    f32x4 acc00 = {0.f, 0.f, 0.f, 0.f};
    f32x4 acc01 = {0.f, 0.f, 0.f, 0.f};
    f32x4 acc10 = {0.f, 0.f, 0.f, 0.f};
    f32x4 acc11 = {0.f, 0.f, 0.f, 0.f};

#pragma unroll 4
    for (int kk = 0; kk < 512; kk += 32) {
        short8 a0 = *(const short8*)(X + kk);
        short8 a1 = *(const short8*)(X + 8192 + kk);   // +16 rows
        short8 b0 = *(const short8*)(Y + kk);
        short8 b1 = *(const short8*)(Y + 8192 + kk);
        acc00 = __builtin_amdgcn_mfma_f32_16x16x32_bf16(a0, b0, acc00, 0, 0, 0);
        acc01 = __builtin_amdgcn_mfma_f32_16x16x32_bf16(a0, b1, acc01, 0, 0, 0);
        acc10 = __builtin_amdgcn_mfma_f32_16x16x32_bf16(a1, b0, acc10, 0, 0, 0);
        acc11 = __builtin_amdgcn_mfma_f32_16x16x32_bf16(a1, b1, acc11, 0, 0, 0);
    }

    int rb = (b << 9) + ti * 64 + wr * 32;
    int cb = (b << 9) + tj * 64 + wc * 32;
    float x2v0[4], x2v1[4];
#pragma unroll
    for (int r = 0; r < 4; ++r) {
        x2v0[r] = x2[rb + lg * 4 + r];
        x2v1[r] = x2[rb + 16 + lg * 4 + r];
    }
    float y2v0 = y2[cb + lr];
    float y2v1 = y2[cb + 16 + lr];

    int d2[2][2][4];
#pragma unroll
    for (int r = 0; r < 4; ++r) {
        d2[0][0][r] = (int)(fmaxf(fmaf(-2.0f, acc00[r], x2v0[r] + y2v0), 0.0f) + 0.5f);
        d2[0][1][r] = (int)(fmaxf(fmaf(-2.0f, acc01[r], x2v0[r] + y2v1), 0.0f) + 0.5f);
        d2[1][0][r] = (int)(fmaxf(fmaf(-2.0f, acc10[r], x2v1[r] + y2v0), 0.0f) + 0.5f);
        d2[1][1][r] = (int)(fmaxf(fmaf(-2.0f, acc11[r], x2v1[r] + y2v1), 0.0f) + 0.5f);
    }

    // row mins: row r held by 16 lanes sharing lg (C layout: col = l&15)
#pragma unroll
    for (int fi = 0; fi < 2; ++fi) {
#pragma unroll
        for (int r = 0; r < 4; ++r) {
            int m = min(d2[fi][0][r], d2[fi][1][r]);
            m = min(m, __shfl_xor(m, 1, 64));
            m = min(m, __shfl_xor(m, 2, 64));
            m = min(m, __shfl_xor(m, 4, 64));
            m = min(m, __shfl_xor(m, 8, 64));
            if (lr == 0) atomicMin(&rowmin[rb + fi * 16 + lg * 4 + r], m);
        }
    }
    // col mins
#pragma unroll
    for (int fj = 0; fj < 2; ++fj) {
        int m;
        if (fj == 0) {
            m = min(min(min(d2[0][0][0], d2[0][0][1]), min(d2[0][0][2], d2[0][0][3])),
                    min(min(d2[1][0][0], d2[1][0][1]), min(d2[1][0][2], d2[1][0][3])));
        } else {
            m = min(min(min(d2[0][1][0], d2[0][1][1]), min(d2[0][1][2], d2[0][1][3])),
                    min(min(d2[1][1][0], d2[1][1][1]), min(d2[1][1][2], d2[1][1][3])));
        }
        m = min(m, __shfl_xor(m, 16, 64));
        m = min(m, __shfl_xor(m, 32, 64));
        if (lg == 0) atomicMin(&colmin[cb + fj * 16 + lr], m);
    }
}

// ---------------- final: per-batch max over (rowmin ∪ colmin), sqrt, mean ----------------
__global__ __launch_bounds__(512) void hd_final(const int* __restrict__ rowmin,
                                                const int* __restrict__ colmin,
                                                float* __restrict__ out) {
    int w = threadIdx.x >> 6, l = threadIdx.x & 63;   // wave w = batch w
    int m = 0;
#pragma unroll
    for (int j = 0; j < 512; j += 64) {
        m = max(m, rowmin[(w << 9) + j + l]);
        m = max(m, colmin[(w << 9) + j + l]);
    }
#pragma unroll
    for (int s = 32; s > 0; s >>= 1) m = max(m, __shfl_xor(m, s, 64));
    __shared__ float hd[8];
    if (l == 0) hd[w] = sqrtf((float)m);
    __syncthreads();
    if (threadIdx.x == 0) {
        float s = 0.0f;
#pragma unroll
        for (int i = 0; i < 8; ++i) s += hd[i];
        out[0] = s * 0.125f;
    }
}

extern "C" void kernel_launch(void* const* d_in, const int* in_sizes, int n_in,
                              void* d_out, int out_size, void* d_ws, size_t ws_size,
                              hipStream_t stream) {
    (void)in_sizes; (void)n_in; (void)out_size; (void)ws_size;
    const float* logits = (const float*)d_in[0];
    const float* target = (const float*)d_in[1];

    char* ws = (char*)d_ws;
    ushort* lxb = (ushort*)ws;                          // 2M bf16 = 4 MB
    ushort* tyb = (ushort*)(ws + (4u << 20));           // 4 MB
    float* x2   = (float*)(ws + (8u << 20));            // 4096 f32
    float* y2   = x2 + 4096;                            // 4096 f32
    int* rowmin = (int*)(y2 + 4096);                    // 4096 i32
    int* colmin = rowmin + 4096;                        // 4096 i32
    float* out  = (float*)d_out;

    hipLaunchKernelGGL(hd_init,   dim3(16),    dim3(256), 0, stream, rowmin, colmin);
    hipLaunchKernelGGL(hd_argmax, dim3(4096),  dim3(256), 0, stream, logits, target, lxb, tyb);
    hipLaunchKernelGGL(hd_norms,  dim3(2048),  dim3(256), 0, stream, lxb, tyb, x2, y2);
    hipLaunchKernelGGL(hd_dist,   dim3(64, 8), dim3(256), 0, stream, lxb, tyb, x2, y2, rowmin, colmin);
    hipLaunchKernelGGL(hd_final,  dim3(1),     dim3(512), 0, stream, rowmin, colmin, out);
}

// Round 4
// 49.888 us; speedup vs baseline: 1.1833x; 1.0953x over previous
//
#include <hip/hip_runtime.h>
#include <hip/hip_bf16.h>
#include <climits>

// Problem constants: B=8, C=8, H=512, W=512
#define HWSZ 262144      // H*W
#define CHWSZ 2097152    // C*H*W

typedef short short8 __attribute__((ext_vector_type(8)));   // 8 bf16 (4 VGPRs)
typedef float f32x4 __attribute__((ext_vector_type(4)));    // MFMA accumulator
typedef unsigned short u16x8 __attribute__((ext_vector_type(8)));  // 16B label chunk

#define GLOAD_LDS16(gp, lp)                                                        \
    __builtin_amdgcn_global_load_lds(                                              \
        (const __attribute__((address_space(1))) unsigned int*)(gp),               \
        (__attribute__((address_space(3))) unsigned int*)(lp), 16, 0, 0)

// ---------------- argmax via global_load_lds staging, bit-reversed block mapping ------
// R1/R3 both plateau at ~3 TB/s effective with ample in-flight bytes (Little's law
// satisfied) while fillBuffer hits 6.7 TB/s -> not latency-bound, not BW-bound:
// the 16 read streams are spaced exactly 2^20 B and concurrent blocks march in phase,
// so the instantaneous footprint aliases onto a subset of HBM channels.
// Fix: chunk = brev12(blockIdx) scatters concurrent blocks' phase windows across the
// whole address range (all channels covered every instant). 2 KB/stream/block bursts
// unchanged.
__global__ __launch_bounds__(256) void hd_argmax(const float* __restrict__ logits,
                                                 const float* __restrict__ target,
                                                 ushort* __restrict__ lxb,
                                                 ushort* __restrict__ tyb) {
    __shared__ float lds[2][8][512];   // 32 KB
    int t = threadIdx.x;
    int l = t & 63, w = t >> 6;
    int chunk = (int)(__brev((unsigned)blockIdx.x) >> 20);   // 12-bit bit-reversal
    int blockpx = chunk * 512;
    int b = blockpx >> 18;
    int off = blockpx & (HWSZ - 1);
    const float* base0 = logits + (size_t)b * CHWSZ + off;
    const float* base1 = target + (size_t)b * CHWSZ + off;

#pragma unroll
    for (int i = 0; i < 8; ++i) {
        int idx = w * 8 + i;                 // 0..31, wave-uniform
        int in = idx >> 4;                   // 0: logits, 1: target
        int ch = (idx >> 1) & 7;
        int hf = idx & 1;                    // half of the 512-px stripe
        const float* gp = (in ? base1 : base0) + ch * HWSZ + hf * 256 + l * 4;  // per-lane 16B
        GLOAD_LDS16(gp, &lds[in][ch][hf * 256]);                                // wave-uniform dest
    }
    __syncthreads();   // compiler emits s_waitcnt vmcnt(0) before the barrier

    // thread t owns pixels blockpx + 2t, 2t+1
#pragma unroll
    for (int in = 0; in < 2; ++in) {
        float2 v0 = *(const float2*)&lds[in][0][t * 2];
        float bx = v0.x, by = v0.y;
        int ix = 0, iy = 0;
#pragma unroll
        for (int c = 1; c < 8; ++c) {
            float2 v = *(const float2*)&lds[in][c][t * 2];
            if (v.x > bx) { bx = v.x; ix = c; }   // strict >: first-max, matches jnp.argmax
            if (v.y > by) { by = v.y; iy = c; }
        }
        ushort2 u;
        u.x = (ushort)(__float_as_uint((float)ix) >> 16);   // exact bf16 for 0..7
        u.y = (ushort)(__float_as_uint((float)iy) >> 16);
        ushort* dst = (in ? tyb : lxb) + blockpx + t * 2;
        *(ushort2*)dst = u;
    }
}

// ---------------- row norms + min-buffer init: one wave per row, no atomics ----------------
__global__ __launch_bounds__(256) void hd_norms(const ushort* __restrict__ lxb,
                                                const ushort* __restrict__ tyb,
                                                float* __restrict__ x2,
                                                float* __restrict__ y2,
                                                int* __restrict__ rowmin,
                                                int* __restrict__ colmin) {
    int gid = blockIdx.x * 256 + threadIdx.x;
    if (gid < 4096) {            // fused init (runs before hd_dist on the same stream)
        rowmin[gid] = INT_MAX;
        colmin[gid] = INT_MAX;
    }
    int wid = blockIdx.x * 4 + (threadIdx.x >> 6);   // 0..8191
    int l = threadIdx.x & 63;
    const ushort* src = (wid < 4096) ? (lxb + wid * 512) : (tyb + (wid - 4096) * 512);
    u16x8 u = *(const u16x8*)(src + l * 8);
    float s = 0.0f;
#pragma unroll
    for (int j = 0; j < 8; ++j) {
        float f = __uint_as_float((unsigned)u[j] << 16);
        s += f * f;
    }
#pragma unroll
    for (int o = 32; o > 0; o >>= 1) s += __shfl_xor(s, o, 64);
    if (l == 0) {
        if (wid < 4096) x2[wid] = s; else y2[wid - 4096] = s;
    }
}

// ---------------- 64x64-tile MFMA distance kernel ----------------
// Grid (64, 8). 4 waves/block, wave (wr,wc) owns a 32x32 quadrant as 2x2 16x16x32 frags.
// Fragments load straight from global (label maps are 512KB/batch -> L2-hot).
// d2 = x2[i] + y2[j] - 2*<x_i,y_j> (exact integer), reduced via shfl + atomicMin.
__global__ __launch_bounds__(256) void hd_dist(const ushort* __restrict__ lxb,
                                               const ushort* __restrict__ tyb,
                                               const float* __restrict__ x2,
                                               const float* __restrict__ y2,
                                               int* __restrict__ rowmin,
                                               int* __restrict__ colmin) {
    int b = blockIdx.y;
    int ti = blockIdx.x >> 3, tj = blockIdx.x & 7;
    int tid = threadIdx.x;
    int l = tid & 63;
    int wv = tid >> 6;
    int wr = wv >> 1, wc = wv & 1;
    int lr = l & 15, lg = l >> 4;

    const ushort* X = lxb + b * HWSZ + (ti * 64 + wr * 32 + lr) * 512 + lg * 8;
    const ushort* Y = tyb + b * HWSZ + (tj * 64 + wc * 32 + lr) * 512 + lg * 8;

    f32x4 acc00 = {0.f, 0.f, 0.f, 0.f};
    f32x4 acc01 = {0.f, 0.f, 0.f, 0.f};
    f32x4 acc10 = {0.f, 0.f, 0.f, 0.f};
    f32x4 acc11 = {0.f, 0.f, 0.f, 0.f};

#pragma unroll 4
    for (int kk = 0; kk < 512; kk += 32) {
        short8 a0 = *(const short8*)(X + kk);
        short8 a1 = *(const short8*)(X + 8192 + kk);   // +16 rows
        short8 b0 = *(const short8*)(Y + kk);
        short8 b1 = *(const short8*)(Y + 8192 + kk);
        acc00 = __builtin_amdgcn_mfma_f32_16x16x32_bf16(a0, b0, acc00, 0, 0, 0);
        acc01 = __builtin_amdgcn_mfma_f32_16x16x32_bf16(a0, b1, acc01, 0, 0, 0);
        acc10 = __builtin_amdgcn_mfma_f32_16x16x32_bf16(a1, b0, acc10, 0, 0, 0);
        acc11 = __builtin_amdgcn_mfma_f32_16x16x32_bf16(a1, b1, acc11, 0, 0, 0);
    }

    int rb = (b << 9) + ti * 64 + wr * 32;
    int cb = (b << 9) + tj * 64 + wc * 32;
    float x2v0[4], x2v1[4];
#pragma unroll
    for (int r = 0; r < 4; ++r) {
        x2v0[r] = x2[rb + lg * 4 + r];
        x2v1[r] = x2[rb + 16 + lg * 4 + r];
    }
    float y2v0 = y2[cb + lr];
    float y2v1 = y2[cb + 16 + lr];

    int d2[2][2][4];
#pragma unroll
    for (int r = 0; r < 4; ++r) {
        d2[0][0][r] = (int)(fmaxf(fmaf(-2.0f, acc00[r], x2v0[r] + y2v0), 0.0f) + 0.5f);
        d2[0][1][r] = (int)(fmaxf(fmaf(-2.0f, acc01[r], x2v0[r] + y2v1), 0.0f) + 0.5f);
        d2[1][0][r] = (int)(fmaxf(fmaf(-2.0f, acc10[r], x2v1[r] + y2v0), 0.0f) + 0.5f);
        d2[1][1][r] = (int)(fmaxf(fmaf(-2.0f, acc11[r], x2v1[r] + y2v1), 0.0f) + 0.5f);
    }

    // row mins: row r held by 16 lanes sharing lg (C layout: col = l&15)
#pragma unroll
    for (int fi = 0; fi < 2; ++fi) {
#pragma unroll
        for (int r = 0; r < 4; ++r) {
            int m = min(d2[fi][0][r], d2[fi][1][r]);
            m = min(m, __shfl_xor(m, 1, 64));
            m = min(m, __shfl_xor(m, 2, 64));
            m = min(m, __shfl_xor(m, 4, 64));
            m = min(m, __shfl_xor(m, 8, 64));
            if (lr == 0) atomicMin(&rowmin[rb + fi * 16 + lg * 4 + r], m);
        }
    }
    // col mins
#pragma unroll
    for (int fj = 0; fj < 2; ++fj) {
        int m;
        if (fj == 0) {
            m = min(min(min(d2[0][0][0], d2[0][0][1]), min(d2[0][0][2], d2[0][0][3])),
                    min(min(d2[1][0][0], d2[1][0][1]), min(d2[1][0][2], d2[1][0][3])));
        } else {
            m = min(min(min(d2[0][1][0], d2[0][1][1]), min(d2[0][1][2], d2[0][1][3])),
                    min(min(d2[1][1][0], d2[1][1][1]), min(d2[1][1][2], d2[1][1][3])));
        }
        m = min(m, __shfl_xor(m, 16, 64));
        m = min(m, __shfl_xor(m, 32, 64));
        if (lg == 0) atomicMin(&colmin[cb + fj * 16 + lr], m);
    }
}

// ---------------- final: per-batch max over (rowmin ∪ colmin), sqrt, mean ----------------
__global__ __launch_bounds__(512) void hd_final(const int* __restrict__ rowmin,
                                                const int* __restrict__ colmin,
                                                float* __restrict__ out) {
    int w = threadIdx.x >> 6, l = threadIdx.x & 63;   // wave w = batch w
    int m = 0;
#pragma unroll
    for (int j = 0; j < 512; j += 64) {
        m = max(m, rowmin[(w << 9) + j + l]);
        m = max(m, colmin[(w << 9) + j + l]);
    }
#pragma unroll
    for (int s = 32; s > 0; s >>= 1) m = max(m, __shfl_xor(m, s, 64));
    __shared__ float hd[8];
    if (l == 0) hd[w] = sqrtf((float)m);
    __syncthreads();
    if (threadIdx.x == 0) {
        float s = 0.0f;
#pragma unroll
        for (int i = 0; i < 8; ++i) s += hd[i];
        out[0] = s * 0.125f;
    }
}

extern "C" void kernel_launch(void* const* d_in, const int* in_sizes, int n_in,
                              void* d_out, int out_size, void* d_ws, size_t ws_size,
                              hipStream_t stream) {
    (void)in_sizes; (void)n_in; (void)out_size; (void)ws_size;
    const float* logits = (const float*)d_in[0];
    const float* target = (const float*)d_in[1];

    char* ws = (char*)d_ws;
    ushort* lxb = (ushort*)ws;                          // 2M bf16 = 4 MB
    ushort* tyb = (ushort*)(ws + (4u << 20));           // 4 MB
    float* x2   = (float*)(ws + (8u << 20));            // 4096 f32
    float* y2   = x2 + 4096;                            // 4096 f32
    int* rowmin = (int*)(y2 + 4096);                    // 4096 i32
    int* colmin = rowmin + 4096;                        // 4096 i32
    float* out  = (float*)d_out;

    hipLaunchKernelGGL(hd_argmax, dim3(4096),  dim3(256), 0, stream, logits, target, lxb, tyb);
    hipLaunchKernelGGL(hd_norms,  dim3(2048),  dim3(256), 0, stream, lxb, tyb, x2, y2, rowmin, colmin);
    hipLaunchKernelGGL(hd_dist,   dim3(64, 8), dim3(256), 0, stream, lxb, tyb, x2, y2, rowmin, colmin);
    hipLaunchKernelGGL(hd_final,  dim3(1),     dim3(512), 0, stream, rowmin, colmin, out);
}